// Round 1
// baseline (903.652 us; speedup 1.0000x reference)
//
#include <hip/hip_runtime.h>

namespace {
constexpr int Bn = 4, Cn = 512, Hn = 96, Wn = 320, Dch = 48;
constexpr int HWn = Hn * Wn;          // 30720
constexpr int WCH = 160;              // w-chunk per block
constexpr int NJ = WCH + Dch - 1;     // 207 staged R columns
constexpr int NJP = 208;              // padded stride (16B-aligned rows)
constexpr int CC = 8;                 // channel chunk
constexpr int NT = 256;               // threads per block
}

__global__ __launch_bounds__(NT)
void cost_volume_kernel(const float* __restrict__ left,
                        const float* __restrict__ right,
                        float* __restrict__ out) {
  __shared__ float Ls[CC * WCH];     // L[c][w]  (local w)
  __shared__ float Rs[CC * NJP];     // R[c][j], j -> w' = wbase+j, zero-padded
  __shared__ float RSs[CC * NJP];    // right_shifted[c][j]
  __shared__ float Rcol[CC * Hn];    // x-interpolated column gather
  __shared__ float f0t[NJP], f1t[NJP];
  __shared__ int   y0t[NJP], y1t[NJP];

  const int tid = threadIdx.x;
  const int wc = blockIdx.x;      // 0..1 w-chunk
  const int h  = blockIdx.y;      // 0..95
  const int b  = blockIdx.z;      // 0..3
  const int w0c = wc * WCH;
  const int wbase = w0c - (Dch - 1);   // w' = wbase + j

  // ---- x-side interpolation params (block-uniform), replicate ref fp32 ops
  const float yv  = -1.0f + 2.0f * (float)h / 96.0f;
  const float xf  = ((yv + 1.0f) * 320.0f - 1.0f) * 0.5f;   // = h*10/3 - 0.5
  const float x0f = floorf(xf);
  const float wx1 = xf - x0f;
  const float wx0 = 1.0f - wx1;
  const int ix0 = (int)x0f;
  const bool mx0 = (ix0 >= 0) && (ix0 < Wn);
  const bool mx1 = (ix0 + 1 >= 0) && (ix0 + 1 < Wn);

  // ---- per-w' y-interpolation tables (masks folded into weights)
  for (int j = tid; j < NJP; j += NT) {
    float ff0 = 0.f, ff1 = 0.f; int yy0 = 0, yy1 = 0;
    int wg = wbase + j;
    if (j < NJ && wg >= 0) {
      float xv = -1.0f + 2.0f * (float)wg / 320.0f - (1.0f / 512.0f);
      float yf = ((xv + 1.0f) * 96.0f - 1.0f) * 0.5f;
      float y0fl = floorf(yf);
      float wy1 = yf - y0fl;
      float wy0 = 1.0f - wy1;
      int iy0 = (int)y0fl;
      if (iy0 >= 0 && iy0 < Hn)         { ff0 = wy0; yy0 = iy0; }
      if (iy0 + 1 >= 0 && iy0 + 1 < Hn) { ff1 = wy1; yy1 = iy0 + 1; }
    }
    f0t[j] = ff0; f1t[j] = ff1; y0t[j] = yy0; y1t[j] = yy1;
  }
  // Rcol rows outside the gathered y-range must be finite (masked-weight reads)
  for (int v = tid; v < CC * Hn; v += NT) Rcol[v] = 0.f;

  // ---- block-uniform y gather range (ypix monotone in w')
  const int wpmin = wbase < 0 ? 0 : wbase;
  const int wpmax = wbase + NJ - 1;   // <= 319
  float xvmin = -1.0f + 2.0f * (float)wpmin / 320.0f - (1.0f / 512.0f);
  float yfmin = ((xvmin + 1.0f) * 96.0f - 1.0f) * 0.5f;
  float xvmax = -1.0f + 2.0f * (float)wpmax / 320.0f - (1.0f / 512.0f);
  float yfmax = ((xvmax + 1.0f) * 96.0f - 1.0f) * 0.5f;
  int ylo = (int)floorf(yfmin); if (ylo < 0) ylo = 0;
  int yhi = (int)floorf(yfmax) + 1; if (yhi > Hn - 1) yhi = Hn - 1;
  const int NY = yhi - ylo + 1;

  // ---- thread -> output tile mapping: 12 d-groups x 20 w-groups = 240 active
  const int dt = tid / 20;
  const int wt = tid % 20;
  const bool active = tid < 240;
  const int d0 = dt * 4;
  const int wl0 = wt * 8;
  const int rbase = wl0 - d0 + (Dch - 4);  // multiple of 4 -> aligned b128 reads

  float acc1[4][8];
  float acc2[4][8];
  #pragma unroll
  for (int j = 0; j < 4; ++j)
    #pragma unroll
    for (int i = 0; i < 8; ++i) { acc1[j][i] = 0.f; acc2[j][i] = 0.f; }

  const int lplane  = (b * Cn) * HWn + h * Wn;  // + c*HWn
  const int rplane  = (b * Cn) * HWn + h * Wn;
  const int rplane0 = (b * Cn) * HWn;           // gather: y varies

  for (int c0 = 0; c0 < Cn; c0 += CC) {
    __syncthreads();  // previous compute done before overwriting LDS
    // stage L (vectorized, coalesced)
    for (int v = tid; v < CC * (WCH / 4); v += NT) {
      int c = v / (WCH / 4);
      int w4 = (v % (WCH / 4)) * 4;
      const float4 val = *reinterpret_cast<const float4*>(
          left + lplane + (c0 + c) * HWn + w0c + w4);
      *reinterpret_cast<float4*>(&Ls[c * WCH + w4]) = val;
    }
    // stage R row with left zero-pad (coalesced scalar)
    for (int v = tid; v < CC * NJP; v += NT) {
      int c = v / NJP;
      int j = v - c * NJP;
      float val = 0.f;
      int wg = wbase + j;
      if (j < NJ && wg >= 0)
        val = right[rplane + (c0 + c) * HWn + wg];
      Rs[c * NJP + j] = val;
    }
    // gather the two x-columns, fold wx weights
    for (int v = tid; v < CC * NY; v += NT) {
      int c = v / NY;
      int yy = ylo + (v - c * NY);
      const float* rp = right + rplane0 + (c0 + c) * HWn + yy * Wn;
      float a  = mx0 ? rp[ix0]     : 0.f;
      float bb = mx1 ? rp[ix0 + 1] : 0.f;
      Rcol[c * Hn + yy] = wx0 * a + wx1 * bb;
    }
    __syncthreads();
    // build right_shifted rows from Rcol (y interpolation)
    for (int v = tid; v < CC * NJP; v += NT) {
      int c = v / NJP;
      int j = v - c * NJP;
      float val = f0t[j] * Rcol[c * Hn + y0t[j]] +
                  f1t[j] * Rcol[c * Hn + y1t[j]];
      RSs[c * NJP + j] = val;
    }
    __syncthreads();
    if (active) {
      #pragma unroll
      for (int c = 0; c < CC; ++c) {
        float lv[8], rv[12], sv[12];
        *reinterpret_cast<float4*>(&lv[0]) =
            *reinterpret_cast<const float4*>(&Ls[c * WCH + wl0]);
        *reinterpret_cast<float4*>(&lv[4]) =
            *reinterpret_cast<const float4*>(&Ls[c * WCH + wl0 + 4]);
        const int rb_ = c * NJP + rbase;
        *reinterpret_cast<float4*>(&rv[0]) =
            *reinterpret_cast<const float4*>(&Rs[rb_]);
        *reinterpret_cast<float4*>(&rv[4]) =
            *reinterpret_cast<const float4*>(&Rs[rb_ + 4]);
        *reinterpret_cast<float4*>(&rv[8]) =
            *reinterpret_cast<const float4*>(&Rs[rb_ + 8]);
        *reinterpret_cast<float4*>(&sv[0]) =
            *reinterpret_cast<const float4*>(&RSs[rb_]);
        *reinterpret_cast<float4*>(&sv[4]) =
            *reinterpret_cast<const float4*>(&RSs[rb_ + 4]);
        *reinterpret_cast<float4*>(&sv[8]) =
            *reinterpret_cast<const float4*>(&RSs[rb_ + 8]);
        #pragma unroll
        for (int j = 0; j < 4; ++j)
          #pragma unroll
          for (int i = 0; i < 8; ++i) {
            acc1[j][i] = fmaf(lv[i], rv[i - j + 3], acc1[j][i]);
            acc2[j][i] = fmaf(lv[i], sv[i - j + 3], acc2[j][i]);
          }
      }
    }
  }

  if (active) {
    const float inv = 1.0f / 512.0f;
    #pragma unroll
    for (int j = 0; j < 4; ++j) {
      const int d = d0 + j;
      float4 o0, o1;
      o0.x = acc1[j][0] * inv; o0.y = acc1[j][1] * inv;
      o0.z = acc1[j][2] * inv; o0.w = acc1[j][3] * inv;
      o1.x = acc1[j][4] * inv; o1.y = acc1[j][5] * inv;
      o1.z = acc1[j][6] * inv; o1.w = acc1[j][7] * inv;
      int oidx = ((b * 96 + d) * Hn + h) * Wn + w0c + wl0;
      *reinterpret_cast<float4*>(out + oidx)     = o0;
      *reinterpret_cast<float4*>(out + oidx + 4) = o1;
      float4 p0, p1;
      p0.x = acc2[j][0] * inv; p0.y = acc2[j][1] * inv;
      p0.z = acc2[j][2] * inv; p0.w = acc2[j][3] * inv;
      p1.x = acc2[j][4] * inv; p1.y = acc2[j][5] * inv;
      p1.z = acc2[j][6] * inv; p1.w = acc2[j][7] * inv;
      int oidx2 = ((b * 96 + (Dch + d)) * Hn + h) * Wn + w0c + wl0;
      *reinterpret_cast<float4*>(out + oidx2)     = p0;
      *reinterpret_cast<float4*>(out + oidx2 + 4) = p1;
    }
  }
}

extern "C" void kernel_launch(void* const* d_in, const int* in_sizes, int n_in,
                              void* d_out, int out_size, void* d_ws, size_t ws_size,
                              hipStream_t stream) {
  const float* left  = (const float*)d_in[0];
  const float* right = (const float*)d_in[1];
  float* out = (float*)d_out;
  (void)in_sizes; (void)n_in; (void)d_ws; (void)ws_size; (void)out_size;
  dim3 grid(2, Hn, Bn);   // (w-chunk, h, b) = 768 blocks
  dim3 block(NT);
  hipLaunchKernelGGL(cost_volume_kernel, grid, block, 0, stream,
                     left, right, out);
}

// Round 4
// 841.415 us; speedup vs baseline: 1.0740x; 1.0740x over previous
//
#include <hip/hip_runtime.h>
#include <stdint.h>

typedef __fp16 f16x2 __attribute__((ext_vector_type(2)));

#ifndef __has_builtin
#define __has_builtin(x) 0
#endif

namespace {
constexpr int Bn = 4, Cn = 512, Hn = 96, Wn = 320, Dch = 48;
constexpr int HWn = Hn * Wn;        // 30720
constexpr int WCH = 160;            // w-chunk per block
constexpr int NJ = WCH + Dch - 1;   // 207 staged R columns (u32 c-pairs)
constexpr int CC = 16;              // channels per chunk
constexpr int CP = 8;               // c-pairs per chunk
constexpr int NCH = Cn / CC;        // 32 chunks
constexpr int QL = 40;              // quads per Ls row (160 u32)
constexpr int QR = 52;              // logical quads per Rs row (208 u32)
constexpr int RSTRIDE = 224;        // u32 stride per Rs/RSs row (56 quads, swizzle headroom)
constexpr int NT = 128;             // threads per block
}

__device__ __forceinline__ uint32_t pk2(float a, float b) {
  f16x2 h = __builtin_amdgcn_cvt_pkrtz(a, b);
  return __builtin_bit_cast(uint32_t, h);
}

__device__ __forceinline__ float dot2f(uint32_t a, uint32_t b, float c) {
#if __has_builtin(__builtin_amdgcn_fdot2)
  return __builtin_amdgcn_fdot2(__builtin_bit_cast(f16x2, a),
                                __builtin_bit_cast(f16x2, b), c, false);
#else
  f16x2 ha = __builtin_bit_cast(f16x2, a);
  f16x2 hb = __builtin_bit_cast(f16x2, b);
  return c + (float)ha.x * (float)hb.x + (float)ha.y * (float)hb.y;
#endif
}

// 16B-quad XOR swizzle: bijective within a row, all LDS accesses are
// quad-aligned b128 so this only permutes quads -> conflict spreading is free.
__device__ __forceinline__ int swzq(int q) { return q ^ ((q >> 3) & 7); }

__global__ __launch_bounds__(NT)
void cost_volume_kernel(const float* __restrict__ left,
                        const float* __restrict__ right,
                        float* __restrict__ out) {
  __shared__ uint32_t Ls[CP * WCH];        // packed (c,c+1) f16 pairs, [cp][w]
  __shared__ uint32_t Rs[CP * RSTRIDE];    // [cp][j], j -> w' = wbase+j (swizzled quads)
  __shared__ uint32_t RSs[CP * RSTRIDE];   // right_shifted, same layout
  __shared__ float Rcol[2][CC * Hn];       // x-interpolated column gather (f32), dbuf
  __shared__ float f0t[QR * 4], f1t[QR * 4];
  __shared__ int   y0t[QR * 4], y1t[QR * 4];

  const int tid = threadIdx.x;
  const int wc = blockIdx.x;      // 0..1
  const int h  = blockIdx.y;      // 0..95
  const int b  = blockIdx.z;      // 0..3
  const int w0c = wc * WCH;
  const int wbase = w0c - (Dch - 1);

  // ---- x-side interpolation params (block-uniform), exact ref fp32 ops
  const float yv  = -1.0f + 2.0f * (float)h / 96.0f;
  const float xf  = ((yv + 1.0f) * 320.0f - 1.0f) * 0.5f;
  const float x0f = floorf(xf);
  const float wx1 = xf - x0f;
  const float wx0 = 1.0f - wx1;
  const int ix0 = (int)x0f;
  const bool mx0 = (ix0 >= 0) && (ix0 < Wn);
  const bool mx1 = (ix0 + 1 >= 0) && (ix0 + 1 < Wn);

  // ---- block-uniform y gather range (ypix monotone increasing in w')
  const int wpmin = wbase < 0 ? 0 : wbase;
  const int wpmax = wbase + NJ - 1;
  float xvmin = -1.0f + 2.0f * (float)wpmin / 320.0f - (1.0f / 512.0f);
  float yfmin = ((xvmin + 1.0f) * 96.0f - 1.0f) * 0.5f;
  float xvmax = -1.0f + 2.0f * (float)wpmax / 320.0f - (1.0f / 512.0f);
  float yfmax = ((xvmax + 1.0f) * 96.0f - 1.0f) * 0.5f;
  int ylo = (int)floorf(yfmin); if (ylo < 0) ylo = 0;
  int yhi = (int)floorf(yfmax) + 1; if (yhi > Hn - 1) yhi = Hn - 1;
  const int NY = yhi - ylo + 1;

  // ---- per-w' y-interpolation tables (masks folded into weights)
  for (int j = tid; j < QR * 4; j += NT) {
    float ff0 = 0.f, ff1 = 0.f; int yy0 = ylo, yy1 = ylo;
    int wg = wbase + j;
    if (j < NJ && wg >= 0) {
      float xv = -1.0f + 2.0f * (float)wg / 320.0f - (1.0f / 512.0f);
      float yf = ((xv + 1.0f) * 96.0f - 1.0f) * 0.5f;
      float y0fl = floorf(yf);
      float wy1 = yf - y0fl;
      float wy0 = 1.0f - wy1;
      int iy0 = (int)y0fl;
      if (iy0 >= 0 && iy0 < Hn)         { ff0 = wy0; yy0 = iy0; }
      if (iy0 + 1 >= 0 && iy0 + 1 < Hn) { ff1 = wy1; yy1 = iy0 + 1; }
    }
    f0t[j] = ff0; f1t[j] = ff1; y0t[j] = yy0; y1t[j] = yy1;
  }
  // zero both Rcol buffers (rows outside [ylo,yhi] must be finite)
  for (int v = tid; v < 2 * CC * Hn; v += NT)
    Rcol[v / (CC * Hn)][v % (CC * Hn)] = 0.f;
  __syncthreads();

  // ---- prologue gather for chunk 0 into buf 0
  {
    for (int t = tid; t < CC * NY; t += NT) {
      int c = t / NY; int yy = ylo + (t - c * NY);
      const float* rp = right + ((size_t)(b * Cn + c) * Hn + yy) * Wn;
      float a  = mx0 ? rp[ix0]     : 0.f;
      float bb = mx1 ? rp[ix0 + 1] : 0.f;
      Rcol[0][c * Hn + yy] = wx0 * a + wx1 * bb;
    }
  }

  // ---- thread -> output tile mapping: 6 d-groups x 20 w-groups = 120 active
  const int dg = tid / 20;
  const int wg = tid % 20;
  const bool active = tid < 120;
  const int d0 = dg * 8;
  const int wl0 = wg * 8;
  const int jb = 8 * (wg - dg) + 40;   // first logical u32 of rv span (mult of 8)
  const int qb = jb >> 2;
  // precomputed swizzled u32 offsets (within-row)
  const int swl0 = swzq(wl0 >> 2) * 4;
  const int swl1 = swzq((wl0 >> 2) + 1) * 4;
  int srv[4];
  #pragma unroll
  for (int k = 0; k < 4; ++k) srv[k] = swzq(qb + k) * 4;

  float acc1[8][8], acc2[8][8];
  #pragma unroll
  for (int jd = 0; jd < 8; ++jd)
    #pragma unroll
    for (int i = 0; i < 8; ++i) { acc1[jd][i] = 0.f; acc2[jd][i] = 0.f; }

  for (int ch = 0; ch < NCH; ++ch) {
    const int c0 = ch * CC;
    const int cur = ch & 1;
    __syncthreads();   // previous compute done before overwriting LDS

    // stage L: packed c-pairs, vectorized loads, b128 swizzled writes
    for (int t = tid; t < CP * QL; t += NT) {
      int cp = t / QL, qw = t - cp * QL;
      const float* l0 = left + ((size_t)(b * Cn + c0 + 2 * cp) * Hn + h) * Wn + w0c + qw * 4;
      const float* l1 = l0 + (size_t)HWn;
      float4 va = *(const float4*)l0;
      float4 vb = *(const float4*)l1;
      *(uint4*)&Ls[cp * WCH + swzq(qw) * 4] =
          make_uint4(pk2(va.x, vb.x), pk2(va.y, vb.y), pk2(va.z, vb.z), pk2(va.w, vb.w));
    }
    // stage R row with left zero-pad
    for (int t = tid; t < CP * QR; t += NT) {
      int cp = t / QR, q = t - cp * QR;
      const float* r0 = right + ((size_t)(b * Cn + c0 + 2 * cp) * Hn + h) * Wn;
      const float* r1 = r0 + (size_t)HWn;
      uint32_t o[4];
      #pragma unroll
      for (int e = 0; e < 4; ++e) {
        int j = 4 * q + e; int wgl = wbase + j;
        float a = 0.f, bb = 0.f;
        if (j < NJ && wgl >= 0) { a = r0[wgl]; bb = r1[wgl]; }
        o[e] = pk2(a, bb);
      }
      *(uint4*)&Rs[cp * RSTRIDE + swzq(q) * 4] = make_uint4(o[0], o[1], o[2], o[3]);
    }
    // build right_shifted rows from Rcol[cur] (y interpolation)
    for (int t = tid; t < CP * QR; t += NT) {
      int cp = t / QR, q = t - cp * QR;
      const float* rc0 = &Rcol[cur][(2 * cp) * Hn];
      const float* rc1 = &Rcol[cur][(2 * cp + 1) * Hn];
      uint32_t o[4];
      #pragma unroll
      for (int e = 0; e < 4; ++e) {
        int j = 4 * q + e;
        float v0 = f0t[j] * rc0[y0t[j]] + f1t[j] * rc0[y1t[j]];
        float v1 = f0t[j] * rc1[y0t[j]] + f1t[j] * rc1[y1t[j]];
        o[e] = pk2(v0, v1);
      }
      *(uint4*)&RSs[cp * RSTRIDE + swzq(q) * 4] = make_uint4(o[0], o[1], o[2], o[3]);
    }
    // gather next chunk's x-interpolated columns into the other buffer
    if (ch + 1 < NCH) {
      const int c0n = c0 + CC;
      for (int t = tid; t < CC * NY; t += NT) {
        int c = t / NY; int yy = ylo + (t - c * NY);
        const float* rp = right + ((size_t)(b * Cn + c0n + c) * Hn + yy) * Wn;
        float a  = mx0 ? rp[ix0]     : 0.f;
        float bb = mx1 ? rp[ix0 + 1] : 0.f;
        Rcol[cur ^ 1][c * Hn + yy] = wx0 * a + wx1 * bb;
      }
    }
    __syncthreads();

    if (active) {
      #pragma unroll
      for (int cp = 0; cp < CP; ++cp) {
        uint32_t lv[8], rv[16];
        *(uint4*)&lv[0] = *(const uint4*)&Ls[cp * WCH + swl0];
        *(uint4*)&lv[4] = *(const uint4*)&Ls[cp * WCH + swl1];
        #pragma unroll
        for (int k = 0; k < 4; ++k)
          *(uint4*)&rv[4 * k] = *(const uint4*)&Rs[cp * RSTRIDE + srv[k]];
        #pragma unroll
        for (int jd = 0; jd < 8; ++jd)
          #pragma unroll
          for (int i = 0; i < 8; ++i)
            acc1[jd][i] = dot2f(lv[i], rv[i - jd + 7], acc1[jd][i]);
        #pragma unroll
        for (int k = 0; k < 4; ++k)
          *(uint4*)&rv[4 * k] = *(const uint4*)&RSs[cp * RSTRIDE + srv[k]];
        #pragma unroll
        for (int jd = 0; jd < 8; ++jd)
          #pragma unroll
          for (int i = 0; i < 8; ++i)
            acc2[jd][i] = dot2f(lv[i], rv[i - jd + 7], acc2[jd][i]);
      }
    }
  }

  if (active) {
    const float inv = 1.0f / 512.0f;
    #pragma unroll
    for (int jd = 0; jd < 8; ++jd) {
      const int d = d0 + jd;
      float4 o0, o1;
      o0.x = acc1[jd][0] * inv; o0.y = acc1[jd][1] * inv;
      o0.z = acc1[jd][2] * inv; o0.w = acc1[jd][3] * inv;
      o1.x = acc1[jd][4] * inv; o1.y = acc1[jd][5] * inv;
      o1.z = acc1[jd][6] * inv; o1.w = acc1[jd][7] * inv;
      size_t oidx = ((size_t)(b * 96 + d) * Hn + h) * Wn + w0c + wl0;
      *(float4*)(out + oidx)     = o0;
      *(float4*)(out + oidx + 4) = o1;
      float4 p0, p1;
      p0.x = acc2[jd][0] * inv; p0.y = acc2[jd][1] * inv;
      p0.z = acc2[jd][2] * inv; p0.w = acc2[jd][3] * inv;
      p1.x = acc2[jd][4] * inv; p1.y = acc2[jd][5] * inv;
      p1.z = acc2[jd][6] * inv; p1.w = acc2[jd][7] * inv;
      size_t oidx2 = ((size_t)(b * 96 + Dch + d) * Hn + h) * Wn + w0c + wl0;
      *(float4*)(out + oidx2)     = p0;
      *(float4*)(out + oidx2 + 4) = p1;
    }
  }
}

extern "C" void kernel_launch(void* const* d_in, const int* in_sizes, int n_in,
                              void* d_out, int out_size, void* d_ws, size_t ws_size,
                              hipStream_t stream) {
  const float* left  = (const float*)d_in[0];
  const float* right = (const float*)d_in[1];
  float* out = (float*)d_out;
  (void)in_sizes; (void)n_in; (void)d_ws; (void)ws_size; (void)out_size;
  dim3 grid(Wn / WCH, Hn, Bn);   // (2, 96, 4) = 768 blocks
  dim3 block(NT);
  hipLaunchKernelGGL(cost_volume_kernel, grid, block, 0, stream,
                     left, right, out);
}